// Round 4
// baseline (297.363 us; speedup 1.0000x reference)
//
#include <hip/hip_runtime.h>
#include <hip/hip_bf16.h>
#include <cstdint>

// Problem constants: B=2, T=2048, D_IN=D_OUT=1024, H=16, DH=64
#define SEQ_T 2048
#define DMODEL 1024
#define NHEAD 16
#define DHEAD 64

typedef __attribute__((ext_vector_type(8))) __bf16 bf16x8;
typedef __attribute__((ext_vector_type(4))) float floatx4;

static __device__ __forceinline__ uint16_t f2bf(float f) {
    union { float f; uint32_t u; } v; v.f = f;
    uint32_t r = v.u + 0x7FFFu + ((v.u >> 16) & 1u);   // RNE
    return (uint16_t)(r >> 16);
}

// ---------------- fp32 -> bf16 straight convert (x) ----------------
__global__ void mha_cvt_x(const float* __restrict__ x, uint16_t* __restrict__ xb) {
    int i = (blockIdx.x * blockDim.x + threadIdx.x) * 4;
    float4 f = *(const float4*)(x + i);
    union { uint16_t u[4]; uint64_t v; } o;
    o.u[0] = f2bf(f.x); o.u[1] = f2bf(f.y); o.u[2] = f2bf(f.z); o.u[3] = f2bf(f.w);
    *(uint64_t*)(xb + i) = o.v;
}

// ------------- fp32 -> bf16 convert + transpose (weights) -------------
__global__ void mha_cvt_wt(const float* __restrict__ W0, const float* __restrict__ W1,
                           const float* __restrict__ W2, const float* __restrict__ W3,
                           uint16_t* __restrict__ T0, uint16_t* __restrict__ T1,
                           uint16_t* __restrict__ T2, uint16_t* __restrict__ T3) {
    const float* W; uint16_t* Tt;
    switch (blockIdx.z) {
        case 0: W = W0; Tt = T0; break;
        case 1: W = W1; Tt = T1; break;
        case 2: W = W2; Tt = T2; break;
        default: W = W3; Tt = T3; break;
    }
    __shared__ float tile[64][65];
    const int c  = threadIdx.x & 63;
    const int r0 = threadIdx.x >> 6;
    const int R0 = blockIdx.y * 64, C0 = blockIdx.x * 64;
#pragma unroll
    for (int rr = 0; rr < 16; ++rr) {
        int r = r0 + rr * 4;
        tile[r][c] = W[(size_t)(R0 + r) * DMODEL + C0 + c];
    }
    __syncthreads();
#pragma unroll
    for (int rr = 0; rr < 16; ++rr) {
        int r = r0 + rr * 4;
        Tt[(size_t)(C0 + r) * DMODEL + R0 + c] = f2bf(tile[c][r]);
    }
}

// ---------------- m97-style bf16 MFMA GEMM, B^T input ----------------
// MODE 0: bf16 row-major out. MODE 1: bf16 per-head transposed out
//         Vt[(b*1024+col)*2048 + t]. MODE 2: fp32 out + bias.
template<int MODE>
__device__ __forceinline__ void gemm128_body(
    const uint16_t* __restrict__ A, const uint16_t* __restrict__ Bt,
    uint16_t* __restrict__ outB, float* __restrict__ outF,
    const float* __restrict__ bias) {
    const int K = DMODEL, N = DMODEL;
    __shared__ uint16_t As[128 * 32];
    __shared__ uint16_t Bs[128 * 32];
    const int tid  = threadIdx.x;
    const int wave = tid >> 6;
    const int lane = tid & 63;
    const int m0 = blockIdx.y * 128;
    const int n0 = blockIdx.x * 128;
    const int lr   = lane & 15;
    const int quad = lane >> 4;
    const int wm = wave >> 1, wn = wave & 1;

    floatx4 acc[4][4];
#pragma unroll
    for (int i = 0; i < 4; ++i)
#pragma unroll
        for (int j = 0; j < 4; ++j) acc[i][j] = (floatx4)0.0f;

    for (int k0 = 0; k0 < K; k0 += 32) {
#pragma unroll
        for (int i = 0; i < 2; ++i) {
            int chunk = i * 256 + wave * 64 + lane;
            int r  = chunk >> 2;
            int c8 = (chunk & 3) * 8;
            const uint16_t* ga = A  + (size_t)(m0 + r) * K + k0 + c8;
            const uint16_t* gb = Bt + (size_t)(n0 + r) * K + k0 + c8;
            uint16_t* la = &As[(size_t)(i * 256 + wave * 64) * 8];
            uint16_t* lb = &Bs[(size_t)(i * 256 + wave * 64) * 8];
            __builtin_amdgcn_global_load_lds((const __attribute__((address_space(1))) void*)ga,
                                             (__attribute__((address_space(3))) void*)la, 16, 0, 0);
            __builtin_amdgcn_global_load_lds((const __attribute__((address_space(1))) void*)gb,
                                             (__attribute__((address_space(3))) void*)lb, 16, 0, 0);
        }
        __syncthreads();
        bf16x8 af[4], bfr[4];
#pragma unroll
        for (int mi = 0; mi < 4; ++mi)
            af[mi] = *(const bf16x8*)&As[(wm * 64 + mi * 16 + lr) * 32 + quad * 8];
#pragma unroll
        for (int ni = 0; ni < 4; ++ni)
            bfr[ni] = *(const bf16x8*)&Bs[(wn * 64 + ni * 16 + lr) * 32 + quad * 8];
#pragma unroll
        for (int mi = 0; mi < 4; ++mi)
#pragma unroll
            for (int ni = 0; ni < 4; ++ni)
                acc[mi][ni] = __builtin_amdgcn_mfma_f32_16x16x32_bf16(af[mi], bfr[ni], acc[mi][ni], 0, 0, 0);
        __syncthreads();
    }
#pragma unroll
    for (int mi = 0; mi < 4; ++mi)
#pragma unroll
        for (int ni = 0; ni < 4; ++ni) {
            int col = n0 + wn * 64 + ni * 16 + lr;
            if (MODE == 1) {
                int row0 = m0 + wm * 64 + mi * 16 + quad * 4;
                union { uint16_t u[4]; uint64_t v8; } pk;
#pragma unroll
                for (int r = 0; r < 4; ++r) pk.u[r] = f2bf(acc[mi][ni][r]);
                int bb = row0 >> 11, t = row0 & 2047;
                *(uint64_t*)&outB[((size_t)(bb * 1024 + col)) * 2048 + t] = pk.v8;
            } else {
#pragma unroll
                for (int r = 0; r < 4; ++r) {
                    int row = m0 + wm * 64 + mi * 16 + quad * 4 + r;
                    float v = acc[mi][ni][r];
                    if (MODE == 2) outF[(size_t)row * N + col] = v + bias[col];
                    else           outB[(size_t)row * N + col] = f2bf(v);
                }
            }
        }
}

__global__ __launch_bounds__(256) void mha_gemm_qkv(
    const uint16_t* __restrict__ A,
    const uint16_t* __restrict__ Wq, const uint16_t* __restrict__ Wk, const uint16_t* __restrict__ Wv,
    uint16_t* __restrict__ Q, uint16_t* __restrict__ K, uint16_t* __restrict__ Vt) {
    switch (blockIdx.z) {
        case 0:  gemm128_body<0>(A, Wq, Q,  nullptr, nullptr); break;
        case 1:  gemm128_body<0>(A, Wk, K,  nullptr, nullptr); break;
        default: gemm128_body<1>(A, Wv, Vt, nullptr, nullptr); break;
    }
}

__global__ __launch_bounds__(256) void mha_gemm_out(
    const uint16_t* __restrict__ A, const uint16_t* __restrict__ Wot,
    float* __restrict__ out, const float* __restrict__ bias) {
    gemm128_body<2>(A, Wot, nullptr, out, bias);
}

// ---------------- MFMA flash attention (causal, fixed-base softmax) -------
// Paired-tile balanced blocks: block p processes q-tile 63-p (heavy, TH
// k-tiles) then q-tile p (light, TL k-tiles); TH+TL = 33/34 uniformly.
// 128 thr = 2 waves, 16 q-rows/wave. K/V double-buffered in LDS with
// register prefetch (global->VGPR issued before compute, ds_write after),
// so the barrier's vmcnt drain finds the loads already complete.
// Fixed-base softmax p=exp(s/8); P truncated to bf16 with l accumulated
// from the truncated value (numerator/denominator consistent).
__global__ __launch_bounds__(128) void mha_attn_mfma(
    const uint16_t* __restrict__ Q, const uint16_t* __restrict__ K,
    const uint16_t* __restrict__ Vt, uint16_t* __restrict__ ctx) {
    __shared__ alignas(16) uint16_t Ks[2][64 * 64];   // 16 KB
    __shared__ alignas(16) uint16_t Vs[2][64 * 64];   // 16 KB
    __shared__ alignas(16) uint16_t Pb[32 * 72];      // 4.5 KB

    const int tid  = threadIdx.x;
    const int wave = tid >> 6;
    const int lane = tid & 63;
    const int lr   = lane & 15;
    const int quad = lane >> 4;
    const int p  = blockIdx.x;             // 0..31
    const int h  = blockIdx.y;
    const int b  = blockIdx.z;
    const int jH = 63 - p, jL = p;
    const int TH = (jH >> 1) + 1;
    const int TL = (jL >> 1) + 1;
    const int Ttot = TH + TL;

    int wrow = jH * 32 + wave * 16;        // current segment's wave q-row base
    bf16x8 qf0, qf1;
    {
        const size_t qb = ((size_t)(b * SEQ_T) + wrow + lr) * DMODEL + h * DHEAD;
        qf0 = *(const bf16x8*)(Q + qb + quad * 8);
        qf1 = *(const bf16x8*)(Q + qb + 32 + quad * 8);
    }
    floatx4 o[4];
#pragma unroll
    for (int nt = 0; nt < 4; ++nt) o[nt] = (floatx4)0.0f;
    float l[4] = {0.f, 0.f, 0.f, 0.f};

    uint4 kr[4], vr[4];
    // prefetch: global -> regs (XOR-swizzled source, linear LDS chunks)
    auto pf = [&](int kv0) {
#pragma unroll
        for (int i = 0; i < 4; ++i) {
            int c = i * 128 + tid;         // chunk 0..511 (16B each)
            int row = c >> 3, cs = c & 7;
            int csk = cs ^ (row & 7);
            kr[i] = *(const uint4*)(K  + ((size_t)(b * SEQ_T) + kv0 + row) * DMODEL + h * DHEAD + csk * 8);
            vr[i] = *(const uint4*)(Vt + ((size_t)(b * 1024 + h * DHEAD + row)) * 2048 + kv0 + csk * 8);
        }
    };
    auto wr = [&](int buf) {
#pragma unroll
        for (int i = 0; i < 4; ++i) {
            int c = i * 128 + tid;
            *(uint4*)&Ks[buf][c * 8] = kr[i];
            *(uint4*)&Vs[buf][c * 8] = vr[i];
        }
    };
    auto epilogue = [&]() {
#pragma unroll
        for (int r = 0; r < 4; ++r) {
            float v = l[r];
            v += __shfl_xor(v, 1, 64);
            v += __shfl_xor(v, 2, 64);
            v += __shfl_xor(v, 4, 64);
            v += __shfl_xor(v, 8, 64);
            l[r] = 1.f / v;
        }
#pragma unroll
        for (int nt = 0; nt < 4; ++nt)
#pragma unroll
            for (int r = 0; r < 4; ++r) {
                size_t addr = ((size_t)(b * SEQ_T) + wrow + quad * 4 + r) * DMODEL + h * DHEAD + nt * 16 + lr;
                ctx[addr] = f2bf(o[nt][r] * l[r]);
            }
    };

    // prologue: stage tile 0 into buf 0
    pf(0);
    wr(0);
    __syncthreads();
    int cur = 0;

    for (int t = 0; t < Ttot; ++t) {
        // issue next tile's global loads early (in flight across compute)
        if (t + 1 < Ttot) {
            int nkv0 = ((t + 1 < TH) ? (t + 1) : (t + 1 - TH)) * 64;
            pf(nkv0);
        }
        const int kv0 = ((t < TH) ? t : (t - TH)) * 64;

        // ---- S = Q K^T : C-layout col(lane&15)=key, row(quad*4+r)=q-row
        floatx4 s[4];
#pragma unroll
        for (int nt = 0; nt < 4; ++nt) {
            s[nt] = (floatx4)0.0f;
            int krow = nt * 16 + lr;
#pragma unroll
            for (int ks = 0; ks < 2; ++ks) {
                bf16x8 kf = *(const bf16x8*)&Ks[cur][krow * 64 + (((ks * 4 + quad) ^ (lr & 7)) * 8)];
                s[nt] = __builtin_amdgcn_mfma_f32_16x16x32_bf16(ks ? qf1 : qf0, kf, s[nt], 0, 0, 0);
            }
        }
        // ---- causal mask (diagonal region only; wave-uniform branch)
        if (kv0 + 63 > wrow) {
#pragma unroll
            for (int nt = 0; nt < 4; ++nt) {
                int kcol = kv0 + nt * 16 + lr;
#pragma unroll
                for (int r = 0; r < 4; ++r) {
                    int qrow = wrow + quad * 4 + r;
                    if (kcol > qrow) s[nt][r] = -3e38f;
                }
            }
        }
        // ---- fixed-base softmax: p = exp(s/8); truncate to bf16, keep
        //      l consistent with the truncated numerator values
#pragma unroll
        for (int nt = 0; nt < 4; ++nt)
#pragma unroll
            for (int r = 0; r < 4; ++r) {
                float pe = __expf(s[nt][r] * 0.125f);
                uint32_t pu = __float_as_uint(pe);
                l[r] += __uint_as_float(pu & 0xffff0000u);
                Pb[(wave * 16 + quad * 4 + r) * 72 + nt * 16 + lr] = (uint16_t)(pu >> 16);
            }
        // ---- O += P V   (wave-private Pb region; compiler inserts lgkm wait)
#pragma unroll
        for (int ks = 0; ks < 2; ++ks) {
            bf16x8 pfr = *(const bf16x8*)&Pb[(wave * 16 + lr) * 72 + ks * 32 + quad * 8];
#pragma unroll
            for (int nt = 0; nt < 4; ++nt) {
                int vrow = nt * 16 + lr;
                bf16x8 vf = *(const bf16x8*)&Vs[cur][vrow * 64 + (((ks * 4 + quad) ^ (lr & 7)) * 8)];
                o[nt] = __builtin_amdgcn_mfma_f32_16x16x32_bf16(pfr, vf, o[nt], 0, 0, 0);
            }
        }
        // ---- segment boundary: store heavy tile, switch to light
        if (t == TH - 1) {
            epilogue();
            wrow = jL * 32 + wave * 16;
            const size_t qb = ((size_t)(b * SEQ_T) + wrow + lr) * DMODEL + h * DHEAD;
            qf0 = *(const bf16x8*)(Q + qb + quad * 8);
            qf1 = *(const bf16x8*)(Q + qb + 32 + quad * 8);
#pragma unroll
            for (int nt = 0; nt < 4; ++nt) o[nt] = (floatx4)0.0f;
#pragma unroll
            for (int r = 0; r < 4; ++r) l[r] = 0.f;
        }
        __syncthreads();                   // all waves done reading buf[cur]
        if (t + 1 < Ttot) wr(cur ^ 1);     // stage next tile into other buf
        __syncthreads();                   // buf[cur^1] ready
        cur ^= 1;
    }
    epilogue();                            // light q-tile output
}

extern "C" void kernel_launch(void* const* d_in, const int* in_sizes, int n_in,
                              void* d_out, int out_size, void* d_ws, size_t ws_size,
                              hipStream_t stream) {
    const float* x  = (const float*)d_in[0];
    const float* Wq = (const float*)d_in[1];
    const float* Wk = (const float*)d_in[2];
    const float* Wv = (const float*)d_in[3];
    const float* Wo = (const float*)d_in[4];
    const float* bo = (const float*)d_in[5];
    float* out = (float*)d_out;

    char* ws = (char*)d_ws;
    const size_t SZ_X = (size_t)4096 * DMODEL * 2;   // 8 MB
    const size_t SZ_W = (size_t)DMODEL * DMODEL * 2; // 2 MB
    size_t off = 0;
    uint16_t* xb  = (uint16_t*)(ws + off); off += SZ_X;
    uint16_t* wqt = (uint16_t*)(ws + off); off += SZ_W;
    uint16_t* wkt = (uint16_t*)(ws + off); off += SZ_W;
    uint16_t* wvt = (uint16_t*)(ws + off); off += SZ_W;
    uint16_t* wot = (uint16_t*)(ws + off); off += SZ_W;
    uint16_t* Qb  = (uint16_t*)(ws + off); off += SZ_X;
    uint16_t* Kb  = (uint16_t*)(ws + off); off += SZ_X;
    uint16_t* Vtb = (uint16_t*)(ws + off); off += SZ_X;  // per-head transposed V
    uint16_t* Cb  = (uint16_t*)(ws + off); off += SZ_X;
    (void)ws_size; (void)in_sizes; (void)n_in; (void)out_size;

    mha_cvt_x<<<4096, 256, 0, stream>>>(x, xb);
    mha_cvt_wt<<<dim3(16, 16, 4), 256, 0, stream>>>(Wq, Wk, Wv, Wo, wqt, wkt, wvt, wot);
    mha_gemm_qkv<<<dim3(8, 32, 3), 256, 0, stream>>>(xb, wqt, wkt, wvt, Qb, Kb, Vtb);
    mha_attn_mfma<<<dim3(32, NHEAD, 2), 128, 0, stream>>>(Qb, Kb, Vtb, Cb);
    mha_gemm_out<<<dim3(8, 32, 1), 256, 0, stream>>>(Cb, wot, out, bo);
}

// Round 5
// 198.635 us; speedup vs baseline: 1.4970x; 1.4970x over previous
//
#include <hip/hip_runtime.h>
#include <hip/hip_bf16.h>
#include <cstdint>

// Problem constants: B=2, T=2048, D_IN=D_OUT=1024, H=16, DH=64
#define SEQ_T 2048
#define DMODEL 1024
#define NHEAD 16
#define DHEAD 64

typedef __attribute__((ext_vector_type(8))) __bf16 bf16x8;
typedef __attribute__((ext_vector_type(4))) float floatx4;

static __device__ __forceinline__ uint16_t f2bf(float f) {
    union { float f; uint32_t u; } v; v.f = f;
    uint32_t r = v.u + 0x7FFFu + ((v.u >> 16) & 1u);   // RNE
    return (uint16_t)(r >> 16);
}

// ---------------- fp32 -> bf16 straight convert (x) ----------------
__global__ void mha_cvt_x(const float* __restrict__ x, uint16_t* __restrict__ xb) {
    int i = (blockIdx.x * blockDim.x + threadIdx.x) * 4;
    float4 f = *(const float4*)(x + i);
    union { uint16_t u[4]; uint64_t v; } o;
    o.u[0] = f2bf(f.x); o.u[1] = f2bf(f.y); o.u[2] = f2bf(f.z); o.u[3] = f2bf(f.w);
    *(uint64_t*)(xb + i) = o.v;
}

// ------------- fp32 -> bf16 convert + transpose (weights) -------------
__global__ void mha_cvt_wt(const float* __restrict__ W0, const float* __restrict__ W1,
                           const float* __restrict__ W2, const float* __restrict__ W3,
                           uint16_t* __restrict__ T0, uint16_t* __restrict__ T1,
                           uint16_t* __restrict__ T2, uint16_t* __restrict__ T3) {
    const float* W; uint16_t* Tt;
    switch (blockIdx.z) {
        case 0: W = W0; Tt = T0; break;
        case 1: W = W1; Tt = T1; break;
        case 2: W = W2; Tt = T2; break;
        default: W = W3; Tt = T3; break;
    }
    __shared__ float tile[64][65];
    const int c  = threadIdx.x & 63;
    const int r0 = threadIdx.x >> 6;
    const int R0 = blockIdx.y * 64, C0 = blockIdx.x * 64;
#pragma unroll
    for (int rr = 0; rr < 16; ++rr) {
        int r = r0 + rr * 4;
        tile[r][c] = W[(size_t)(R0 + r) * DMODEL + C0 + c];
    }
    __syncthreads();
#pragma unroll
    for (int rr = 0; rr < 16; ++rr) {
        int r = r0 + rr * 4;
        Tt[(size_t)(C0 + r) * DMODEL + R0 + c] = f2bf(tile[c][r]);
    }
}

// ---------------- m97-style bf16 MFMA GEMM, B^T input ----------------
// MODE 0: bf16 row-major out. MODE 1: bf16 per-head transposed out
//         Vt[(b*1024+col)*2048 + t]. MODE 2: fp32 out + bias.
template<int MODE>
__device__ __forceinline__ void gemm128_body(
    const uint16_t* __restrict__ A, const uint16_t* __restrict__ Bt,
    uint16_t* __restrict__ outB, float* __restrict__ outF,
    const float* __restrict__ bias) {
    const int K = DMODEL, N = DMODEL;
    __shared__ uint16_t As[128 * 32];
    __shared__ uint16_t Bs[128 * 32];
    const int tid  = threadIdx.x;
    const int wave = tid >> 6;
    const int lane = tid & 63;
    const int m0 = blockIdx.y * 128;
    const int n0 = blockIdx.x * 128;
    const int lr   = lane & 15;
    const int quad = lane >> 4;
    const int wm = wave >> 1, wn = wave & 1;

    floatx4 acc[4][4];
#pragma unroll
    for (int i = 0; i < 4; ++i)
#pragma unroll
        for (int j = 0; j < 4; ++j) acc[i][j] = (floatx4)0.0f;

    for (int k0 = 0; k0 < K; k0 += 32) {
#pragma unroll
        for (int i = 0; i < 2; ++i) {
            int chunk = i * 256 + wave * 64 + lane;
            int r  = chunk >> 2;
            int c8 = (chunk & 3) * 8;
            const uint16_t* ga = A  + (size_t)(m0 + r) * K + k0 + c8;
            const uint16_t* gb = Bt + (size_t)(n0 + r) * K + k0 + c8;
            uint16_t* la = &As[(size_t)(i * 256 + wave * 64) * 8];
            uint16_t* lb = &Bs[(size_t)(i * 256 + wave * 64) * 8];
            __builtin_amdgcn_global_load_lds((const __attribute__((address_space(1))) void*)ga,
                                             (__attribute__((address_space(3))) void*)la, 16, 0, 0);
            __builtin_amdgcn_global_load_lds((const __attribute__((address_space(1))) void*)gb,
                                             (__attribute__((address_space(3))) void*)lb, 16, 0, 0);
        }
        __syncthreads();
        bf16x8 af[4], bfr[4];
#pragma unroll
        for (int mi = 0; mi < 4; ++mi)
            af[mi] = *(const bf16x8*)&As[(wm * 64 + mi * 16 + lr) * 32 + quad * 8];
#pragma unroll
        for (int ni = 0; ni < 4; ++ni)
            bfr[ni] = *(const bf16x8*)&Bs[(wn * 64 + ni * 16 + lr) * 32 + quad * 8];
#pragma unroll
        for (int mi = 0; mi < 4; ++mi)
#pragma unroll
            for (int ni = 0; ni < 4; ++ni)
                acc[mi][ni] = __builtin_amdgcn_mfma_f32_16x16x32_bf16(af[mi], bfr[ni], acc[mi][ni], 0, 0, 0);
        __syncthreads();
    }
#pragma unroll
    for (int mi = 0; mi < 4; ++mi)
#pragma unroll
        for (int ni = 0; ni < 4; ++ni) {
            int col = n0 + wn * 64 + ni * 16 + lr;
            if (MODE == 1) {
                int row0 = m0 + wm * 64 + mi * 16 + quad * 4;
                union { uint16_t u[4]; uint64_t v8; } pk;
#pragma unroll
                for (int r = 0; r < 4; ++r) pk.u[r] = f2bf(acc[mi][ni][r]);
                int bb = row0 >> 11, t = row0 & 2047;
                *(uint64_t*)&outB[((size_t)(bb * 1024 + col)) * 2048 + t] = pk.v8;
            } else {
#pragma unroll
                for (int r = 0; r < 4; ++r) {
                    int row = m0 + wm * 64 + mi * 16 + quad * 4 + r;
                    float v = acc[mi][ni][r];
                    if (MODE == 2) outF[(size_t)row * N + col] = v + bias[col];
                    else           outB[(size_t)row * N + col] = f2bf(v);
                }
            }
        }
}

__global__ __launch_bounds__(256) void mha_gemm_qkv(
    const uint16_t* __restrict__ A,
    const uint16_t* __restrict__ Wq, const uint16_t* __restrict__ Wk, const uint16_t* __restrict__ Wv,
    uint16_t* __restrict__ Q, uint16_t* __restrict__ K, uint16_t* __restrict__ Vt) {
    switch (blockIdx.z) {
        case 0:  gemm128_body<0>(A, Wq, Q,  nullptr, nullptr); break;
        case 1:  gemm128_body<0>(A, Wk, K,  nullptr, nullptr); break;
        default: gemm128_body<1>(A, Wv, Vt, nullptr, nullptr); break;
    }
}

__global__ __launch_bounds__(256) void mha_gemm_out(
    const uint16_t* __restrict__ A, const uint16_t* __restrict__ Wot,
    float* __restrict__ out, const float* __restrict__ bias) {
    gemm128_body<2>(A, Wot, nullptr, out, bias);
}

// ---------------- MFMA flash attention (causal, fixed-base softmax) -------
// Balanced pairing: block p does q-tile 63-p (heavy) then q-tile p (light);
// TH+TL = 33/34 k-tile iterations for every block -> uniform finish.
// Async double-buffer: global_load_lds for tile t+1 issues into buf^1
// BEFORE compute on buf (loads in flight behind MFMA+softmax), then a
// single barrier per iteration both finishes reads-of-cur and drains the
// prefetch. No VGPR staging -> no scratch spill (R4's failure mode).
__global__ __launch_bounds__(128) void mha_attn_mfma(
    const uint16_t* __restrict__ Q, const uint16_t* __restrict__ K,
    const uint16_t* __restrict__ Vt, uint16_t* __restrict__ ctx) {
    __shared__ alignas(16) uint16_t Ks[2][64 * 64];   // 16 KB
    __shared__ alignas(16) uint16_t Vs[2][64 * 64];   // 16 KB
    __shared__ alignas(16) uint16_t Pb[32 * 72];      // 4.5 KB

    const int tid  = threadIdx.x;
    const int wave = tid >> 6;
    const int lane = tid & 63;
    const int lr   = lane & 15;
    const int quad = lane >> 4;
    const int p  = blockIdx.x;             // 0..31
    const int h  = blockIdx.y;
    const int b  = blockIdx.z;
    const int jH = 63 - p, jL = p;
    const int TH = (jH >> 1) + 1;
    const int TL = (jL >> 1) + 1;
    const int Ttot = TH + TL;

    int wrow = jH * 32 + wave * 16;        // current segment's wave q-row base
    bf16x8 qf0, qf1;
    {
        const size_t qb = ((size_t)(b * SEQ_T) + wrow + lr) * DMODEL + h * DHEAD;
        qf0 = *(const bf16x8*)(Q + qb + quad * 8);
        qf1 = *(const bf16x8*)(Q + qb + 32 + quad * 8);
    }
    floatx4 o[4];
#pragma unroll
    for (int nt = 0; nt < 4; ++nt) o[nt] = (floatx4)0.0f;
    float l[4] = {0.f, 0.f, 0.f, 0.f};

    // async stage of one 64-key K/V tile into LDS buffer `buf`
    auto stage = [&](int kv0, int buf) {
#pragma unroll
        for (int i = 0; i < 4; ++i) {
            int c = i * 128 + tid;         // chunk 0..511 (16B each)
            int row = c >> 3, cs = c & 7;
            int csk = cs ^ (row & 7);      // XOR source swizzle; dest linear
            const uint16_t* gk = K  + ((size_t)(b * SEQ_T) + kv0 + row) * DMODEL + h * DHEAD + csk * 8;
            const uint16_t* gv = Vt + ((size_t)(b * 1024 + h * DHEAD + row)) * 2048 + kv0 + csk * 8;
            uint16_t* lk = &Ks[buf][(i * 128 + wave * 64) * 8];
            uint16_t* lv = &Vs[buf][(i * 128 + wave * 64) * 8];
            __builtin_amdgcn_global_load_lds((const __attribute__((address_space(1))) void*)gk,
                                             (__attribute__((address_space(3))) void*)lk, 16, 0, 0);
            __builtin_amdgcn_global_load_lds((const __attribute__((address_space(1))) void*)gv,
                                             (__attribute__((address_space(3))) void*)lv, 16, 0, 0);
        }
    };
    auto epilogue = [&]() {
#pragma unroll
        for (int r = 0; r < 4; ++r) {
            float v = l[r];
            v += __shfl_xor(v, 1, 64);
            v += __shfl_xor(v, 2, 64);
            v += __shfl_xor(v, 4, 64);
            v += __shfl_xor(v, 8, 64);
            l[r] = 1.f / v;
        }
#pragma unroll
        for (int nt = 0; nt < 4; ++nt)
#pragma unroll
            for (int r = 0; r < 4; ++r) {
                size_t addr = ((size_t)(b * SEQ_T) + wrow + quad * 4 + r) * DMODEL + h * DHEAD + nt * 16 + lr;
                ctx[addr] = f2bf(o[nt][r] * l[r]);
            }
    };

    stage(0, 0);
    __syncthreads();                       // tile 0 ready
    int cur = 0;

    for (int t = 0; t < Ttot; ++t) {
        // issue next tile's direct-to-LDS loads into the other buffer;
        // they fly behind this iteration's compute
        if (t + 1 < Ttot) {
            int nkv0 = ((t + 1 < TH) ? (t + 1) : (t + 1 - TH)) * 64;
            stage(nkv0, cur ^ 1);
        }
        const int kv0 = ((t < TH) ? t : (t - TH)) * 64;

        // ---- S = Q K^T : C-layout col(lane&15)=key, row(quad*4+r)=q-row
        floatx4 s[4];
#pragma unroll
        for (int nt = 0; nt < 4; ++nt) {
            s[nt] = (floatx4)0.0f;
            int krow = nt * 16 + lr;
#pragma unroll
            for (int ks = 0; ks < 2; ++ks) {
                bf16x8 kf = *(const bf16x8*)&Ks[cur][krow * 64 + (((ks * 4 + quad) ^ (lr & 7)) * 8)];
                s[nt] = __builtin_amdgcn_mfma_f32_16x16x32_bf16(ks ? qf1 : qf0, kf, s[nt], 0, 0, 0);
            }
        }
        // ---- causal mask (diagonal region only; wave-uniform branch)
        if (kv0 + 63 > wrow) {
#pragma unroll
            for (int nt = 0; nt < 4; ++nt) {
                int kcol = kv0 + nt * 16 + lr;
#pragma unroll
                for (int r = 0; r < 4; ++r) {
                    int qrow = wrow + quad * 4 + r;
                    if (kcol > qrow) s[nt][r] = -3e38f;
                }
            }
        }
        // ---- fixed-base softmax: p = exp(s/8); truncate to bf16, keep
        //      l consistent with the truncated numerator values
#pragma unroll
        for (int nt = 0; nt < 4; ++nt)
#pragma unroll
            for (int r = 0; r < 4; ++r) {
                float pe = __expf(s[nt][r] * 0.125f);
                uint32_t pu = __float_as_uint(pe);
                l[r] += __uint_as_float(pu & 0xffff0000u);
                Pb[(wave * 16 + quad * 4 + r) * 72 + nt * 16 + lr] = (uint16_t)(pu >> 16);
            }
        // ---- O += P V   (wave-private Pb region; compiler inserts lgkm wait)
#pragma unroll
        for (int ks = 0; ks < 2; ++ks) {
            bf16x8 pfr = *(const bf16x8*)&Pb[(wave * 16 + lr) * 72 + ks * 32 + quad * 8];
#pragma unroll
            for (int nt = 0; nt < 4; ++nt) {
                int vrow = nt * 16 + lr;
                bf16x8 vf = *(const bf16x8*)&Vs[cur][vrow * 64 + (((ks * 4 + quad) ^ (lr & 7)) * 8)];
                o[nt] = __builtin_amdgcn_mfma_f32_16x16x32_bf16(pfr, vf, o[nt], 0, 0, 0);
            }
        }
        // ---- segment boundary: store heavy tile output, switch to light
        if (t == TH - 1) {
            epilogue();
            wrow = jL * 32 + wave * 16;
            const size_t qb = ((size_t)(b * SEQ_T) + wrow + lr) * DMODEL + h * DHEAD;
            qf0 = *(const bf16x8*)(Q + qb + quad * 8);
            qf1 = *(const bf16x8*)(Q + qb + 32 + quad * 8);
#pragma unroll
            for (int nt = 0; nt < 4; ++nt) o[nt] = (floatx4)0.0f;
#pragma unroll
            for (int r = 0; r < 4; ++r) l[r] = 0.f;
        }
        // single barrier: finishes all reads of buf[cur] AND (via the
        // implicit vmcnt drain) completes the prefetch into buf[cur^1]
        __syncthreads();
        cur ^= 1;
    }
    epilogue();                            // light q-tile output
}

extern "C" void kernel_launch(void* const* d_in, const int* in_sizes, int n_in,
                              void* d_out, int out_size, void* d_ws, size_t ws_size,
                              hipStream_t stream) {
    const float* x  = (const float*)d_in[0];
    const float* Wq = (const float*)d_in[1];
    const float* Wk = (const float*)d_in[2];
    const float* Wv = (const float*)d_in[3];
    const float* Wo = (const float*)d_in[4];
    const float* bo = (const float*)d_in[5];
    float* out = (float*)d_out;

    char* ws = (char*)d_ws;
    const size_t SZ_X = (size_t)4096 * DMODEL * 2;   // 8 MB
    const size_t SZ_W = (size_t)DMODEL * DMODEL * 2; // 2 MB
    size_t off = 0;
    uint16_t* xb  = (uint16_t*)(ws + off); off += SZ_X;
    uint16_t* wqt = (uint16_t*)(ws + off); off += SZ_W;
    uint16_t* wkt = (uint16_t*)(ws + off); off += SZ_W;
    uint16_t* wvt = (uint16_t*)(ws + off); off += SZ_W;
    uint16_t* wot = (uint16_t*)(ws + off); off += SZ_W;
    uint16_t* Qb  = (uint16_t*)(ws + off); off += SZ_X;
    uint16_t* Kb  = (uint16_t*)(ws + off); off += SZ_X;
    uint16_t* Vtb = (uint16_t*)(ws + off); off += SZ_X;  // per-head transposed V
    uint16_t* Cb  = (uint16_t*)(ws + off); off += SZ_X;
    (void)ws_size; (void)in_sizes; (void)n_in; (void)out_size;

    mha_cvt_x<<<4096, 256, 0, stream>>>(x, xb);
    mha_cvt_wt<<<dim3(16, 16, 4), 256, 0, stream>>>(Wq, Wk, Wv, Wo, wqt, wkt, wvt, wot);
    mha_gemm_qkv<<<dim3(8, 32, 3), 256, 0, stream>>>(xb, wqt, wkt, wvt, Qb, Kb, Vtb);
    mha_attn_mfma<<<dim3(32, NHEAD, 2), 128, 0, stream>>>(Qb, Kb, Vtb, Cb);
    mha_gemm_out<<<dim3(8, 32, 1), 256, 0, stream>>>(Cb, wot, out, bo);
}

// Round 6
// 197.091 us; speedup vs baseline: 1.5088x; 1.0078x over previous
//
#include <hip/hip_runtime.h>
#include <hip/hip_bf16.h>
#include <cstdint>

// Problem constants: B=2, T=2048, D_IN=D_OUT=1024, H=16, DH=64
#define SEQ_T 2048
#define DMODEL 1024
#define NHEAD 16
#define DHEAD 64

typedef __attribute__((ext_vector_type(8))) __bf16 bf16x8;
typedef __attribute__((ext_vector_type(4))) float floatx4;

static __device__ __forceinline__ uint16_t f2bf(float f) {
    union { float f; uint32_t u; } v; v.f = f;
    uint32_t r = v.u + 0x7FFFu + ((v.u >> 16) & 1u);   // RNE
    return (uint16_t)(r >> 16);
}

// ---------------- fp32 -> bf16 straight convert (x) ----------------
__global__ void mha_cvt_x(const float* __restrict__ x, uint16_t* __restrict__ xb) {
    int i = (blockIdx.x * blockDim.x + threadIdx.x) * 4;
    float4 f = *(const float4*)(x + i);
    union { uint16_t u[4]; uint64_t v; } o;
    o.u[0] = f2bf(f.x); o.u[1] = f2bf(f.y); o.u[2] = f2bf(f.z); o.u[3] = f2bf(f.w);
    *(uint64_t*)(xb + i) = o.v;
}

// ------------- fp32 -> bf16 convert + transpose (weights) -------------
__global__ void mha_cvt_wt(const float* __restrict__ W0, const float* __restrict__ W1,
                           const float* __restrict__ W2, const float* __restrict__ W3,
                           uint16_t* __restrict__ T0, uint16_t* __restrict__ T1,
                           uint16_t* __restrict__ T2, uint16_t* __restrict__ T3) {
    const float* W; uint16_t* Tt;
    switch (blockIdx.z) {
        case 0: W = W0; Tt = T0; break;
        case 1: W = W1; Tt = T1; break;
        case 2: W = W2; Tt = T2; break;
        default: W = W3; Tt = T3; break;
    }
    __shared__ float tile[64][65];
    const int c  = threadIdx.x & 63;
    const int r0 = threadIdx.x >> 6;
    const int R0 = blockIdx.y * 64, C0 = blockIdx.x * 64;
#pragma unroll
    for (int rr = 0; rr < 16; ++rr) {
        int r = r0 + rr * 4;
        tile[r][c] = W[(size_t)(R0 + r) * DMODEL + C0 + c];
    }
    __syncthreads();
#pragma unroll
    for (int rr = 0; rr < 16; ++rr) {
        int r = r0 + rr * 4;
        Tt[(size_t)(C0 + r) * DMODEL + R0 + c] = f2bf(tile[c][r]);
    }
}

// -------- bf16 MFMA GEMM, B^T input, single-barrier async dbuf --------
// Stage k+32 into buf^1 BEFORE computing on buf; one barrier per k-iter
// both ends reads-of-cur and drains the prefetch (R5-proven pattern).
// MODE 0: bf16 row-major out. MODE 1: bf16 per-head transposed out
//         Vt[(b*1024+col)*2048 + t]. MODE 2: fp32 out + bias.
template<int MODE>
__device__ __forceinline__ void gemm128_body(
    const uint16_t* __restrict__ A, const uint16_t* __restrict__ Bt,
    uint16_t* __restrict__ outB, float* __restrict__ outF,
    const float* __restrict__ bias) {
    const int K = DMODEL, N = DMODEL;
    __shared__ uint16_t As[2][128 * 32];   // 16 KB
    __shared__ uint16_t Bs[2][128 * 32];   // 16 KB
    const int tid  = threadIdx.x;
    const int wave = tid >> 6;
    const int lane = tid & 63;
    const int m0 = blockIdx.y * 128;
    const int n0 = blockIdx.x * 128;
    const int lr   = lane & 15;
    const int quad = lane >> 4;
    const int wm = wave >> 1, wn = wave & 1;

    floatx4 acc[4][4];
#pragma unroll
    for (int i = 0; i < 4; ++i)
#pragma unroll
        for (int j = 0; j < 4; ++j) acc[i][j] = (floatx4)0.0f;

    auto stage = [&](int k0, int buf) {
#pragma unroll
        for (int i = 0; i < 2; ++i) {
            int chunk = i * 256 + wave * 64 + lane;
            int r  = chunk >> 2;
            int c8 = (chunk & 3) * 8;
            const uint16_t* ga = A  + (size_t)(m0 + r) * K + k0 + c8;
            const uint16_t* gb = Bt + (size_t)(n0 + r) * K + k0 + c8;
            uint16_t* la = &As[buf][(size_t)(i * 256 + wave * 64) * 8];
            uint16_t* lb = &Bs[buf][(size_t)(i * 256 + wave * 64) * 8];
            __builtin_amdgcn_global_load_lds((const __attribute__((address_space(1))) void*)ga,
                                             (__attribute__((address_space(3))) void*)la, 16, 0, 0);
            __builtin_amdgcn_global_load_lds((const __attribute__((address_space(1))) void*)gb,
                                             (__attribute__((address_space(3))) void*)lb, 16, 0, 0);
        }
    };

    stage(0, 0);
    __syncthreads();
    int cur = 0;
    for (int k0 = 0; k0 < K; k0 += 32) {
        if (k0 + 32 < K) stage(k0 + 32, cur ^ 1);   // flies behind compute
        bf16x8 af[4], bfr[4];
#pragma unroll
        for (int mi = 0; mi < 4; ++mi)
            af[mi] = *(const bf16x8*)&As[cur][(wm * 64 + mi * 16 + lr) * 32 + quad * 8];
#pragma unroll
        for (int ni = 0; ni < 4; ++ni)
            bfr[ni] = *(const bf16x8*)&Bs[cur][(wn * 64 + ni * 16 + lr) * 32 + quad * 8];
#pragma unroll
        for (int mi = 0; mi < 4; ++mi)
#pragma unroll
            for (int ni = 0; ni < 4; ++ni)
                acc[mi][ni] = __builtin_amdgcn_mfma_f32_16x16x32_bf16(af[mi], bfr[ni], acc[mi][ni], 0, 0, 0);
        __syncthreads();                            // reads done + prefetch drained
        cur ^= 1;
    }
#pragma unroll
    for (int mi = 0; mi < 4; ++mi)
#pragma unroll
        for (int ni = 0; ni < 4; ++ni) {
            int col = n0 + wn * 64 + ni * 16 + lr;
            if (MODE == 1) {
                int row0 = m0 + wm * 64 + mi * 16 + quad * 4;
                union { uint16_t u[4]; uint64_t v8; } pk;
#pragma unroll
                for (int r = 0; r < 4; ++r) pk.u[r] = f2bf(acc[mi][ni][r]);
                int bb = row0 >> 11, t = row0 & 2047;
                *(uint64_t*)&outB[((size_t)(bb * 1024 + col)) * 2048 + t] = pk.v8;
            } else {
#pragma unroll
                for (int r = 0; r < 4; ++r) {
                    int row = m0 + wm * 64 + mi * 16 + quad * 4 + r;
                    float v = acc[mi][ni][r];
                    if (MODE == 2) outF[(size_t)row * N + col] = v + bias[col];
                    else           outB[(size_t)row * N + col] = f2bf(v);
                }
            }
        }
}

__global__ __launch_bounds__(256) void mha_gemm_qkv(
    const uint16_t* __restrict__ A,
    const uint16_t* __restrict__ Wq, const uint16_t* __restrict__ Wk, const uint16_t* __restrict__ Wv,
    uint16_t* __restrict__ Q, uint16_t* __restrict__ K, uint16_t* __restrict__ Vt) {
    switch (blockIdx.z) {
        case 0:  gemm128_body<0>(A, Wq, Q,  nullptr, nullptr); break;
        case 1:  gemm128_body<0>(A, Wk, K,  nullptr, nullptr); break;
        default: gemm128_body<1>(A, Wv, Vt, nullptr, nullptr); break;
    }
}

__global__ __launch_bounds__(256) void mha_gemm_out(
    const uint16_t* __restrict__ A, const uint16_t* __restrict__ Wot,
    float* __restrict__ out, const float* __restrict__ bias) {
    gemm128_body<2>(A, Wot, nullptr, out, bias);
}

// ---------------- MFMA flash attention (causal, fixed-base softmax) -------
// 4 waves / 256 thr per block; one (b,h, 64-row q-tile-pair) per block.
// All 4 waves share each staged 64-key K/V tile -> 2x compute per staged
// byte vs R5 and half the global K/V re-reads. Balanced pairing: block p
// does q-tile 31-p (heavy) then p (light); TH+TL = 33 uniformly.
// Async single-barrier double-buffer staging (R5 pattern). Fixed-base
// softmax p=exp(s/8), P truncated to bf16 with l kept consistent.
__global__ __launch_bounds__(256) void mha_attn_mfma(
    const uint16_t* __restrict__ Q, const uint16_t* __restrict__ K,
    const uint16_t* __restrict__ Vt, uint16_t* __restrict__ ctx) {
    __shared__ alignas(16) uint16_t Ks[2][64 * 64];   // 16 KB
    __shared__ alignas(16) uint16_t Vs[2][64 * 64];   // 16 KB
    __shared__ alignas(16) uint16_t Pb[64 * 72];      // 9 KB

    const int tid  = threadIdx.x;
    const int wave = tid >> 6;
    const int lane = tid & 63;
    const int lr   = lane & 15;
    const int quad = lane >> 4;
    const int p  = blockIdx.x;             // 0..15
    const int h  = blockIdx.y;
    const int b  = blockIdx.z;
    const int jH = 31 - p, jL = p;         // 64-row q-tiles
    const int TH = jH + 1;
    const int TL = jL + 1;
    const int Ttot = TH + TL;              // 33 for every block

    int wrow = jH * 64 + wave * 16;        // this wave's q-row base
    bf16x8 qf0, qf1;
    {
        const size_t qb = ((size_t)(b * SEQ_T) + wrow + lr) * DMODEL + h * DHEAD;
        qf0 = *(const bf16x8*)(Q + qb + quad * 8);
        qf1 = *(const bf16x8*)(Q + qb + 32 + quad * 8);
    }
    floatx4 o[4];
#pragma unroll
    for (int nt = 0; nt < 4; ++nt) o[nt] = (floatx4)0.0f;
    float l[4] = {0.f, 0.f, 0.f, 0.f};

    // async stage of one 64-key K/V tile into LDS buffer `buf`
    auto stage = [&](int kv0, int buf) {
#pragma unroll
        for (int i = 0; i < 2; ++i) {
            int c = i * 256 + tid;         // chunk 0..511 (16B each)
            int row = c >> 3, cs = c & 7;
            int csk = cs ^ (row & 7);      // XOR source swizzle; dest linear
            const uint16_t* gk = K  + ((size_t)(b * SEQ_T) + kv0 + row) * DMODEL + h * DHEAD + csk * 8;
            const uint16_t* gv = Vt + ((size_t)(b * 1024 + h * DHEAD + row)) * 2048 + kv0 + csk * 8;
            uint16_t* lk = &Ks[buf][(i * 256 + wave * 64) * 8];
            uint16_t* lv = &Vs[buf][(i * 256 + wave * 64) * 8];
            __builtin_amdgcn_global_load_lds((const __attribute__((address_space(1))) void*)gk,
                                             (__attribute__((address_space(3))) void*)lk, 16, 0, 0);
            __builtin_amdgcn_global_load_lds((const __attribute__((address_space(1))) void*)gv,
                                             (__attribute__((address_space(3))) void*)lv, 16, 0, 0);
        }
    };
    auto epilogue = [&]() {
#pragma unroll
        for (int r = 0; r < 4; ++r) {
            float v = l[r];
            v += __shfl_xor(v, 1, 64);
            v += __shfl_xor(v, 2, 64);
            v += __shfl_xor(v, 4, 64);
            v += __shfl_xor(v, 8, 64);
            l[r] = 1.f / v;
        }
#pragma unroll
        for (int nt = 0; nt < 4; ++nt)
#pragma unroll
            for (int r = 0; r < 4; ++r) {
                size_t addr = ((size_t)(b * SEQ_T) + wrow + quad * 4 + r) * DMODEL + h * DHEAD + nt * 16 + lr;
                ctx[addr] = f2bf(o[nt][r] * l[r]);
            }
    };

    stage(0, 0);
    __syncthreads();                       // tile 0 ready
    int cur = 0;

    for (int t = 0; t < Ttot; ++t) {
        if (t + 1 < Ttot) {
            int nkv0 = ((t + 1 < TH) ? (t + 1) : (t + 1 - TH)) * 64;
            stage(nkv0, cur ^ 1);          // in flight behind compute
        }
        const int kv0 = ((t < TH) ? t : (t - TH)) * 64;

        // ---- S = Q K^T : C-layout col(lane&15)=key, row(quad*4+r)=q-row
        floatx4 s[4];
#pragma unroll
        for (int nt = 0; nt < 4; ++nt) {
            s[nt] = (floatx4)0.0f;
            int krow = nt * 16 + lr;
#pragma unroll
            for (int ks = 0; ks < 2; ++ks) {
                bf16x8 kf = *(const bf16x8*)&Ks[cur][krow * 64 + (((ks * 4 + quad) ^ (lr & 7)) * 8)];
                s[nt] = __builtin_amdgcn_mfma_f32_16x16x32_bf16(ks ? qf1 : qf0, kf, s[nt], 0, 0, 0);
            }
        }
        // ---- causal mask (diagonal tile only; wave-uniform branch)
        if (kv0 + 63 > wrow) {
#pragma unroll
            for (int nt = 0; nt < 4; ++nt) {
                int kcol = kv0 + nt * 16 + lr;
#pragma unroll
                for (int r = 0; r < 4; ++r) {
                    int qrow = wrow + quad * 4 + r;
                    if (kcol > qrow) s[nt][r] = -3e38f;
                }
            }
        }
        // ---- fixed-base softmax: p = exp(s/8); truncate to bf16, keep
        //      l consistent with the truncated numerator values
#pragma unroll
        for (int nt = 0; nt < 4; ++nt)
#pragma unroll
            for (int r = 0; r < 4; ++r) {
                float pe = __expf(s[nt][r] * 0.125f);
                uint32_t pu = __float_as_uint(pe);
                l[r] += __uint_as_float(pu & 0xffff0000u);
                Pb[(wave * 16 + quad * 4 + r) * 72 + nt * 16 + lr] = (uint16_t)(pu >> 16);
            }
        // ---- O += P V   (wave-private Pb region; same-wave LDS dep)
#pragma unroll
        for (int ks = 0; ks < 2; ++ks) {
            bf16x8 pfr = *(const bf16x8*)&Pb[(wave * 16 + lr) * 72 + ks * 32 + quad * 8];
#pragma unroll
            for (int nt = 0; nt < 4; ++nt) {
                int vrow = nt * 16 + lr;
                bf16x8 vf = *(const bf16x8*)&Vs[cur][vrow * 64 + (((ks * 4 + quad) ^ (lr & 7)) * 8)];
                o[nt] = __builtin_amdgcn_mfma_f32_16x16x32_bf16(pfr, vf, o[nt], 0, 0, 0);
            }
        }
        // ---- segment boundary: store heavy tile output, switch to light
        if (t == TH - 1) {
            epilogue();
            wrow = jL * 64 + wave * 16;
            const size_t qb = ((size_t)(b * SEQ_T) + wrow + lr) * DMODEL + h * DHEAD;
            qf0 = *(const bf16x8*)(Q + qb + quad * 8);
            qf1 = *(const bf16x8*)(Q + qb + 32 + quad * 8);
#pragma unroll
            for (int nt = 0; nt < 4; ++nt) o[nt] = (floatx4)0.0f;
#pragma unroll
            for (int r = 0; r < 4; ++r) l[r] = 0.f;
        }
        // single barrier: finishes all reads of buf[cur] AND (via implicit
        // vmcnt drain) completes the prefetch into buf[cur^1]
        __syncthreads();
        cur ^= 1;
    }
    epilogue();                            // light q-tile output
}

extern "C" void kernel_launch(void* const* d_in, const int* in_sizes, int n_in,
                              void* d_out, int out_size, void* d_ws, size_t ws_size,
                              hipStream_t stream) {
    const float* x  = (const float*)d_in[0];
    const float* Wq = (const float*)d_in[1];
    const float* Wk = (const float*)d_in[2];
    const float* Wv = (const float*)d_in[3];
    const float* Wo = (const float*)d_in[4];
    const float* bo = (const float*)d_in[5];
    float* out = (float*)d_out;

    char* ws = (char*)d_ws;
    const size_t SZ_X = (size_t)4096 * DMODEL * 2;   // 8 MB
    const size_t SZ_W = (size_t)DMODEL * DMODEL * 2; // 2 MB
    size_t off = 0;
    uint16_t* xb  = (uint16_t*)(ws + off); off += SZ_X;
    uint16_t* wqt = (uint16_t*)(ws + off); off += SZ_W;
    uint16_t* wkt = (uint16_t*)(ws + off); off += SZ_W;
    uint16_t* wvt = (uint16_t*)(ws + off); off += SZ_W;
    uint16_t* wot = (uint16_t*)(ws + off); off += SZ_W;
    uint16_t* Qb  = (uint16_t*)(ws + off); off += SZ_X;
    uint16_t* Kb  = (uint16_t*)(ws + off); off += SZ_X;
    uint16_t* Vtb = (uint16_t*)(ws + off); off += SZ_X;  // per-head transposed V
    uint16_t* Cb  = (uint16_t*)(ws + off); off += SZ_X;
    (void)ws_size; (void)in_sizes; (void)n_in; (void)out_size;

    mha_cvt_x<<<4096, 256, 0, stream>>>(x, xb);
    mha_cvt_wt<<<dim3(16, 16, 4), 256, 0, stream>>>(Wq, Wk, Wv, Wo, wqt, wkt, wvt, wot);
    mha_gemm_qkv<<<dim3(8, 32, 3), 256, 0, stream>>>(xb, wqt, wkt, wvt, Qb, Kb, Vtb);
    mha_attn_mfma<<<dim3(16, NHEAD, 2), 256, 0, stream>>>(Qb, Kb, Vtb, Cb);
    mha_gemm_out<<<dim3(8, 32, 1), 256, 0, stream>>>(Cb, wot, out, bo);
}